// Round 1
// baseline (17480.246 us; speedup 1.0000x reference)
//
#include <hip/hip_runtime.h>
#include <stdint.h>

typedef unsigned short u16;
typedef __attribute__((ext_vector_type(8))) short short8;
typedef __attribute__((ext_vector_type(4))) float f32x4;

#define NB 64
#define NT 512
#define ND 1024
#define NG 4096

__device__ __forceinline__ u16 f2bf(float f) {
  uint32_t u = __builtin_bit_cast(uint32_t, f);
  uint32_t r = (u + 0x7fffu + ((u >> 16) & 1u)) >> 16;
  return (u16)r;
}
__device__ __forceinline__ float bf2f(u16 h) {
  uint32_t u = ((uint32_t)h) << 16;
  return __builtin_bit_cast(float, u);
}
__device__ __forceinline__ float sigmf(float x) { return 1.f / (1.f + __expf(-x)); }
__device__ __forceinline__ float tanhf2(float x) { return 1.f - 2.f / (__expf(2.f * x) + 1.f); }

__device__ __forceinline__ void gload16(const void* g, void* l) {
  __builtin_amdgcn_global_load_lds(
      (const __attribute__((address_space(1))) uint32_t*)g,
      (__attribute__((address_space(3))) uint32_t*)l, 16, 0, 0);
}

// ---------------- init: zero h buffer 0 and flags ----------------
__global__ void k_init(uint4* __restrict__ h0, uint4* __restrict__ flags) {
  int i = blockIdx.x * blockDim.x + threadIdx.x;
  if (i < 8192) h0[i] = uint4{0, 0, 0, 0};             // 131072 B = h_dbuf[0]
  else if (i < 8192 + 64) flags[i - 8192] = uint4{0, 0, 0, 0};  // 1024 B flags
}

__global__ void k_wsfail(float* out) {
  int i = blockIdx.x * blockDim.x + threadIdx.x;
  if (i < NB * ND) out[i] = -777.0f;
}

// ---------------- convert x, W_ih to bf16; bias = b_ih + b_hh ----------------
__global__ void k_convert(const float* __restrict__ x, const float* __restrict__ wih,
                          const float* __restrict__ bih, const float* __restrict__ bhh,
                          u16* __restrict__ xb, u16* __restrict__ wb, float* __restrict__ bias) {
  const int NXC = NB * NT * ND / 8;  // 4194304
  const int NWC = NG * ND / 8;       // 524288
  const int NBC = NG / 8;            // 512
  const int tot = NXC + NWC + NBC;
  for (int c = blockIdx.x * blockDim.x + threadIdx.x; c < tot; c += gridDim.x * blockDim.x) {
    if (c < NXC) {
      const float4* s = (const float4*)x + (size_t)c * 2;
      float4 a = s[0], b = s[1];
      short8 v;
      v[0] = (short)f2bf(a.x); v[1] = (short)f2bf(a.y); v[2] = (short)f2bf(a.z); v[3] = (short)f2bf(a.w);
      v[4] = (short)f2bf(b.x); v[5] = (short)f2bf(b.y); v[6] = (short)f2bf(b.z); v[7] = (short)f2bf(b.w);
      *(short8*)(xb + (size_t)c * 8) = v;
    } else if (c < NXC + NWC) {
      int cc = c - NXC;
      const float4* s = (const float4*)wih + (size_t)cc * 2;
      float4 a = s[0], b = s[1];
      short8 v;
      v[0] = (short)f2bf(a.x); v[1] = (short)f2bf(a.y); v[2] = (short)f2bf(a.z); v[3] = (short)f2bf(a.w);
      v[4] = (short)f2bf(b.x); v[5] = (short)f2bf(b.y); v[6] = (short)f2bf(b.z); v[7] = (short)f2bf(b.w);
      *(short8*)(wb + (size_t)cc * 8) = v;
    } else {
      int cc = c - NXC - NWC;
      float4 a0 = ((const float4*)bih)[cc * 2], a1 = ((const float4*)bih)[cc * 2 + 1];
      float4 b0 = ((const float4*)bhh)[cc * 2], b1 = ((const float4*)bhh)[cc * 2 + 1];
      ((float4*)bias)[cc * 2] = float4{a0.x + b0.x, a0.y + b0.y, a0.z + b0.z, a0.w + b0.w};
      ((float4*)bias)[cc * 2 + 1] = float4{a1.x + b1.x, a1.y + b1.y, a1.z + b1.z, a1.w + b1.w};
    }
  }
}

// ---------------- phase 1: xg = x @ W_ih^T + bias  (bf16 out) ----------------
// A [32768][1024] bf16, Bw [4096][1024] bf16 (B^T layout), C [32768][4096] bf16
__global__ __launch_bounds__(256) void k_gemm(const u16* __restrict__ A,
                                              const u16* __restrict__ Bw,
                                              const float* __restrict__ bias,
                                              u16* __restrict__ C) {
  __shared__ u16 As[128 * 32];
  __shared__ u16 Bs[128 * 32];
  const int t = threadIdx.x;
  const int lane = t & 63;
  const int n0 = lane & 15, kg = lane >> 4;
  const int w = t >> 6, wr = w >> 1, wc = w & 1;
  const int bn = blockIdx.x & 31, bm = blockIdx.x >> 5;
  const size_t rowA0 = (size_t)bm * 128, rowB0 = (size_t)bn * 128;

  const u16* gA0 = A + (rowA0 + (t >> 2)) * 1024 + (t & 3) * 8;
  const u16* gA1 = A + (rowA0 + 64 + (t >> 2)) * 1024 + (t & 3) * 8;
  const u16* gB0 = Bw + (rowB0 + (t >> 2)) * 1024 + (t & 3) * 8;
  const u16* gB1 = Bw + (rowB0 + 64 + (t >> 2)) * 1024 + (t & 3) * 8;
  char* lA0 = (char*)As + (t & ~63) * 16;
  char* lA1 = (char*)As + 4096 + (t & ~63) * 16;
  char* lB0 = (char*)Bs + (t & ~63) * 16;
  char* lB1 = (char*)Bs + 4096 + (t & ~63) * 16;

  f32x4 acc[4][4];
#pragma unroll
  for (int i = 0; i < 4; ++i)
#pragma unroll
    for (int j = 0; j < 4; ++j) acc[i][j] = f32x4{0.f, 0.f, 0.f, 0.f};

  for (int it = 0; it < 32; ++it) {
    const int k0 = it * 32;
    __syncthreads();
    gload16(gA0 + k0, lA0);
    gload16(gA1 + k0, lA1);
    gload16(gB0 + k0, lB0);
    gload16(gB1 + k0, lB1);
    asm volatile("s_waitcnt vmcnt(0)" ::: "memory");
    __syncthreads();
    short8 af[4], bf[4];
#pragma unroll
    for (int mi = 0; mi < 4; ++mi)
      af[mi] = *(const short8*)(As + (wr * 64 + mi * 16 + n0) * 32 + kg * 8);
#pragma unroll
    for (int ni = 0; ni < 4; ++ni)
      bf[ni] = *(const short8*)(Bs + (wc * 64 + ni * 16 + n0) * 32 + kg * 8);
#pragma unroll
    for (int mi = 0; mi < 4; ++mi)
#pragma unroll
      for (int ni = 0; ni < 4; ++ni)
        acc[mi][ni] = __builtin_amdgcn_mfma_f32_16x16x32_bf16(af[mi], bf[ni], acc[mi][ni], 0, 0, 0);
  }

  float bz[4];
#pragma unroll
  for (int ni = 0; ni < 4; ++ni) bz[ni] = bias[bn * 128 + wc * 64 + ni * 16 + n0];
#pragma unroll
  for (int mi = 0; mi < 4; ++mi) {
#pragma unroll
    for (int ni = 0; ni < 4; ++ni) {
      const size_t col = rowB0 + wc * 64 + ni * 16 + n0;
#pragma unroll
      for (int r = 0; r < 4; ++r) {
        const size_t gr = rowA0 + wr * 64 + mi * 16 + kg * 4 + r;
        C[gr * NG + col] = f2bf(acc[mi][ni][r] + bz[ni]);
      }
    }
  }
}

// ---------------- phase 2: persistent recurrent scan ----------------
// 256 blocks x 128 threads. block = (group g0 in {0,1} of 32 batch rows) x (cb: 8 h-cols).
// W_hh slice (32 rows x 1024) lives in LDS (bf16, XOR-swizzled). One flag-sync per step.
__global__ __launch_bounds__(128) void k_scan(const float* __restrict__ Whh,
                                              const u16* __restrict__ xg,
                                              u16* __restrict__ hbuf,
                                              int* flags,
                                              float* __restrict__ out) {
  __shared__ u16 Ws[32 * 1024];  // 64 KB
  const int bid = blockIdx.x;
  const int g0 = bid >> 7, cb = bid & 127;
  const int t = threadIdx.x;
  const int lane = t & 63, wv = t >> 6;

  // stage W_hh rows {gate*1024 + cb*8 + hc} -> Ws[r=gate*8+hc][k], XOR-swizzled 16B chunks
  for (int r = 0; r < 32; ++r) {
    const int j = ((r >> 3) << 10) + cb * 8 + (r & 7);
    const float4* src = (const float4*)(Whh + (size_t)j * 1024 + t * 8);
    float4 w0 = src[0], w1 = src[1];
    short8 wvv;
    wvv[0] = (short)f2bf(w0.x); wvv[1] = (short)f2bf(w0.y);
    wvv[2] = (short)f2bf(w0.z); wvv[3] = (short)f2bf(w0.w);
    wvv[4] = (short)f2bf(w1.x); wvv[5] = (short)f2bf(w1.y);
    wvv[6] = (short)f2bf(w1.z); wvv[7] = (short)f2bf(w1.w);
    *(short8*)(Ws + r * 1024 + ((t ^ (r & 7)) * 8)) = wvv;
  }
  __syncthreads();

  const int n0 = lane & 15;      // frag col / A row within 16
  const int hc = lane & 7;
  const int rgrp = lane >> 4;
  const int j0 = ((n0 >> 3) << 10) + cb * 8 + hc;  // gate 0 (i) or 1 (f)
  const int j1 = j0 + 2048;                        // gate 2 (g) or 3 (o)
  const int bbase = g0 * 32 + wv * 16;
  const int brow = bbase + n0;
  int* gf = flags + g0 * 128;

  float c[4] = {0.f, 0.f, 0.f, 0.f};

  for (int s = 0; s < NT; ++s) {
    // prefetch xg for this step (independent of h)
    u16 xva[4], xvb[4];
#pragma unroll
    for (int r = 0; r < 4; ++r) {
      const size_t base = ((size_t)(bbase + rgrp * 4 + r) * NT + s) * NG;
      xva[r] = xg[base + j0];
      xvb[r] = xg[base + j1];
    }

    if (s) {
      for (int it = 0; it < (1 << 17); ++it) {
        int a = __hip_atomic_load(gf + lane * 2, __ATOMIC_RELAXED, __HIP_MEMORY_SCOPE_AGENT);
        int b = __hip_atomic_load(gf + lane * 2 + 1, __ATOMIC_RELAXED, __HIP_MEMORY_SCOPE_AGENT);
        int m = a < b ? a : b;
#pragma unroll
        for (int o = 1; o < 64; o <<= 1) {
          int q = __shfl_xor(m, o, 64);
          m = m < q ? m : q;
        }
        if (m >= s) break;
        __builtin_amdgcn_s_sleep(2);
      }
      __threadfence();  // acquire: see other blocks' h stores
    }

    const u16* hrow = hbuf + (s & 1) * (NB * ND) + (size_t)brow * ND + rgrp * 8;
    f32x4 acc0 = {0.f, 0.f, 0.f, 0.f}, acc1 = {0.f, 0.f, 0.f, 0.f};
#pragma unroll 16
    for (int kk = 0; kk < 32; ++kk) {
      short8 av = *(const short8*)(hrow + kk * 32);
      const int chs = (kk * 4 + rgrp) ^ (n0 & 7);
      short8 b0 = *(const short8*)(Ws + n0 * 1024 + chs * 8);
      short8 b1 = *(const short8*)(Ws + (16 + n0) * 1024 + chs * 8);
      acc0 = __builtin_amdgcn_mfma_f32_16x16x32_bf16(av, b0, acc0, 0, 0, 0);
      acc1 = __builtin_amdgcn_mfma_f32_16x16x32_bf16(av, b1, acc1, 0, 0, 0);
    }

    const bool lo = (lane & 8) == 0;
    u16* hw = hbuf + ((s & 1) ^ 1) * (NB * ND);
#pragma unroll
    for (int r = 0; r < 4; ++r) {
      float pre0 = acc0[r] + bf2f(xva[r]);
      float pre1 = acc1[r] + bf2f(xvb[r]);
      float q0 = __shfl_xor(pre0, 8, 64);
      float q1 = __shfl_xor(pre1, 8, 64);
      float ipre = lo ? pre0 : q0;
      float fpre = lo ? q0 : pre0;
      float gpre = lo ? pre1 : q1;
      float opre = lo ? q1 : pre1;
      float ig = sigmf(ipre), fg = sigmf(fpre), gg = tanhf2(gpre), og = sigmf(opre);
      c[r] = fg * c[r] + ig * gg;
      float h = og * tanhf2(c[r]);
      if (lo) {
        const int b = bbase + rgrp * 4 + r;
        const int hcol = cb * 8 + hc;
        hw[(size_t)b * ND + hcol] = f2bf(h);
        if (s == NT - 1) out[(size_t)b * ND + hcol] = h;
      }
    }
    __threadfence();   // release: h stores visible device-wide
    __syncthreads();   // both waves done before flag bump
    if (t == 0) __hip_atomic_store(&gf[cb], s + 1, __ATOMIC_RELEASE, __HIP_MEMORY_SCOPE_AGENT);
  }
}

extern "C" void kernel_launch(void* const* d_in, const int* in_sizes, int n_in,
                              void* d_out, int out_size, void* d_ws, size_t ws_size,
                              hipStream_t stream) {
  const float* x = (const float*)d_in[0];
  const float* Wih = (const float*)d_in[1];
  const float* Whh = (const float*)d_in[2];
  const float* bih = (const float*)d_in[3];
  const float* bhh = (const float*)d_in[4];
  float* out = (float*)d_out;
  char* ws = (char*)d_ws;

  const size_t SZ_XB = (size_t)NB * NT * ND * 2;   // 67,108,864
  const size_t SZ_XG = (size_t)NB * NT * NG * 2;   // 268,435,456
  const size_t SZ_WB = (size_t)NG * ND * 2;        // 8,388,608
  const size_t SZ_BIAS = (size_t)NG * 4;           // 16,384
  const size_t SZ_H = (size_t)2 * NB * ND * 2;     // 262,144
  const size_t SZ_FLAGS = 1024;
  const size_t NEED = SZ_XB + SZ_XG + SZ_WB + SZ_BIAS + SZ_H + SZ_FLAGS;

  if (ws_size < NEED) {  // sentinel so the failure mode is identifiable
    k_wsfail<<<256, 256, 0, stream>>>(out);
    return;
  }

  size_t off = 0;
  u16* xb = (u16*)(ws + off); off += SZ_XB;
  u16* xg = (u16*)(ws + off); off += SZ_XG;
  u16* wb = (u16*)(ws + off); off += SZ_WB;
  float* bias = (float*)(ws + off); off += SZ_BIAS;
  u16* hbuf = (u16*)(ws + off); off += SZ_H;
  int* flags = (int*)(ws + off); off += SZ_FLAGS;

  k_init<<<33, 256, 0, stream>>>((uint4*)hbuf, (uint4*)flags);
  k_convert<<<2048, 256, 0, stream>>>(x, Wih, bih, bhh, xb, wb, bias);
  k_gemm<<<8192, 256, 0, stream>>>(xb, wb, bias, xg);
  k_scan<<<256, 128, 0, stream>>>(Whh, xg, hbuf, flags, out);
}

// Round 2
// 6665.533 us; speedup vs baseline: 2.6225x; 2.6225x over previous
//
#include <hip/hip_runtime.h>
#include <stdint.h>

typedef unsigned short u16;
typedef unsigned int u32;
typedef unsigned long long u64;
typedef __attribute__((ext_vector_type(8))) short short8;
typedef __attribute__((ext_vector_type(4))) float f32x4;

#define NB 64
#define NT 512
#define ND 1024
#define NG 4096

__device__ __forceinline__ u16 f2bf(float f) {
  uint32_t u = __builtin_bit_cast(uint32_t, f);
  uint32_t r = (u + 0x7fffu + ((u >> 16) & 1u)) >> 16;
  return (u16)r;
}
__device__ __forceinline__ float bf2f(u16 h) {
  uint32_t u = ((uint32_t)h) << 16;
  return __builtin_bit_cast(float, u);
}
__device__ __forceinline__ float sigmf(float x) { return 1.f / (1.f + __expf(-x)); }
__device__ __forceinline__ float tanhf2(float x) { return 1.f - 2.f / (__expf(2.f * x) + 1.f); }

__device__ __forceinline__ void gload16(const void* g, void* l) {
  __builtin_amdgcn_global_load_lds(
      (const __attribute__((address_space(1))) uint32_t*)g,
      (__attribute__((address_space(3))) uint32_t*)l, 16, 0, 0);
}

// ---------------- init: zero h buffer 0 and flags ----------------
__global__ void k_init(uint4* __restrict__ h0, uint4* __restrict__ flags) {
  int i = blockIdx.x * blockDim.x + threadIdx.x;
  if (i < 8192) h0[i] = uint4{0, 0, 0, 0};                      // 131072 B = h_dbuf[0]
  else if (i < 8192 + 64) flags[i - 8192] = uint4{0, 0, 0, 0};  // 1024 B flags
}

__global__ void k_wsfail(float* out) {
  int i = blockIdx.x * blockDim.x + threadIdx.x;
  if (i < NB * ND) out[i] = -777.0f;
}

// ---------------- convert x, W_ih to bf16; bias = b_ih + b_hh ----------------
__global__ void k_convert(const float* __restrict__ x, const float* __restrict__ wih,
                          const float* __restrict__ bih, const float* __restrict__ bhh,
                          u16* __restrict__ xb, u16* __restrict__ wb, float* __restrict__ bias) {
  const int NXC = NB * NT * ND / 8;  // 4194304
  const int NWC = NG * ND / 8;       // 524288
  const int NBC = NG / 8;            // 512
  const int tot = NXC + NWC + NBC;
  for (int c = blockIdx.x * blockDim.x + threadIdx.x; c < tot; c += gridDim.x * blockDim.x) {
    if (c < NXC) {
      const float4* s = (const float4*)x + (size_t)c * 2;
      float4 a = s[0], b = s[1];
      short8 v;
      v[0] = (short)f2bf(a.x); v[1] = (short)f2bf(a.y); v[2] = (short)f2bf(a.z); v[3] = (short)f2bf(a.w);
      v[4] = (short)f2bf(b.x); v[5] = (short)f2bf(b.y); v[6] = (short)f2bf(b.z); v[7] = (short)f2bf(b.w);
      *(short8*)(xb + (size_t)c * 8) = v;
    } else if (c < NXC + NWC) {
      int cc = c - NXC;
      const float4* s = (const float4*)wih + (size_t)cc * 2;
      float4 a = s[0], b = s[1];
      short8 v;
      v[0] = (short)f2bf(a.x); v[1] = (short)f2bf(a.y); v[2] = (short)f2bf(a.z); v[3] = (short)f2bf(a.w);
      v[4] = (short)f2bf(b.x); v[5] = (short)f2bf(b.y); v[6] = (short)f2bf(b.z); v[7] = (short)f2bf(b.w);
      *(short8*)(wb + (size_t)cc * 8) = v;
    } else {
      int cc = c - NXC - NWC;
      float4 a0 = ((const float4*)bih)[cc * 2], a1 = ((const float4*)bih)[cc * 2 + 1];
      float4 b0 = ((const float4*)bhh)[cc * 2], b1 = ((const float4*)bhh)[cc * 2 + 1];
      ((float4*)bias)[cc * 2] = float4{a0.x + b0.x, a0.y + b0.y, a0.z + b0.z, a0.w + b0.w};
      ((float4*)bias)[cc * 2 + 1] = float4{a1.x + b1.x, a1.y + b1.y, a1.z + b1.z, a1.w + b1.w};
    }
  }
}

// ---------------- phase 1: xg = x @ W_ih^T + bias  (bf16 out) ----------------
__global__ __launch_bounds__(256) void k_gemm(const u16* __restrict__ A,
                                              const u16* __restrict__ Bw,
                                              const float* __restrict__ bias,
                                              u16* __restrict__ C) {
  __shared__ u16 As[128 * 32];
  __shared__ u16 Bs[128 * 32];
  const int t = threadIdx.x;
  const int lane = t & 63;
  const int n0 = lane & 15, kg = lane >> 4;
  const int w = t >> 6, wr = w >> 1, wc = w & 1;
  const int bn = blockIdx.x & 31, bm = blockIdx.x >> 5;
  const size_t rowA0 = (size_t)bm * 128, rowB0 = (size_t)bn * 128;

  const u16* gA0 = A + (rowA0 + (t >> 2)) * 1024 + (t & 3) * 8;
  const u16* gA1 = A + (rowA0 + 64 + (t >> 2)) * 1024 + (t & 3) * 8;
  const u16* gB0 = Bw + (rowB0 + (t >> 2)) * 1024 + (t & 3) * 8;
  const u16* gB1 = Bw + (rowB0 + 64 + (t >> 2)) * 1024 + (t & 3) * 8;
  char* lA0 = (char*)As + (t & ~63) * 16;
  char* lA1 = (char*)As + 4096 + (t & ~63) * 16;
  char* lB0 = (char*)Bs + (t & ~63) * 16;
  char* lB1 = (char*)Bs + 4096 + (t & ~63) * 16;

  f32x4 acc[4][4];
#pragma unroll
  for (int i = 0; i < 4; ++i)
#pragma unroll
    for (int j = 0; j < 4; ++j) acc[i][j] = f32x4{0.f, 0.f, 0.f, 0.f};

  for (int it = 0; it < 32; ++it) {
    const int k0 = it * 32;
    __syncthreads();
    gload16(gA0 + k0, lA0);
    gload16(gA1 + k0, lA1);
    gload16(gB0 + k0, lB0);
    gload16(gB1 + k0, lB1);
    asm volatile("s_waitcnt vmcnt(0)" ::: "memory");
    __syncthreads();
    short8 af[4], bf[4];
#pragma unroll
    for (int mi = 0; mi < 4; ++mi)
      af[mi] = *(const short8*)(As + (wr * 64 + mi * 16 + n0) * 32 + kg * 8);
#pragma unroll
    for (int ni = 0; ni < 4; ++ni)
      bf[ni] = *(const short8*)(Bs + (wc * 64 + ni * 16 + n0) * 32 + kg * 8);
#pragma unroll
    for (int mi = 0; mi < 4; ++mi)
#pragma unroll
      for (int ni = 0; ni < 4; ++ni)
        acc[mi][ni] = __builtin_amdgcn_mfma_f32_16x16x32_bf16(af[mi], bf[ni], acc[mi][ni], 0, 0, 0);
  }

  float bz[4];
#pragma unroll
  for (int ni = 0; ni < 4; ++ni) bz[ni] = bias[bn * 128 + wc * 64 + ni * 16 + n0];
#pragma unroll
  for (int mi = 0; mi < 4; ++mi) {
#pragma unroll
    for (int ni = 0; ni < 4; ++ni) {
      const size_t col = rowB0 + wc * 64 + ni * 16 + n0;
#pragma unroll
      for (int r = 0; r < 4; ++r) {
        const size_t gr = rowA0 + wr * 64 + mi * 16 + kg * 4 + r;
        C[gr * NG + col] = f2bf(acc[mi][ni][r] + bz[ni]);
      }
    }
  }
}

// ---------------- phase 2: persistent recurrent scan v2 ----------------
// 64 blocks x 512 threads (8 waves). Block bid owns h-cols [bid*16, bid*16+16),
// all 4 gates: W rows ordered r = hcol_local*4 + gate in 128KB LDS (XOR swizzle).
// Wave wv: n-tile (batch group) nt = wv&3, m-tiles {2*(wv>>2), 2*(wv>>2)+1}.
// MFMA C frag: col = batch, row = kg*4 + r  ->  lane holds ALL 4 gates of one
// (batch, hcol). h exchanged via relaxed agent-scope u64 atomic stores (L3
// write-through); flag = release atomic; readers poll relaxed (wave 0) + one
// acquire load (buffer_inv) + barrier, then plain b128 loads.
__global__ __launch_bounds__(512) void k_scan2(const float* __restrict__ Whh,
                                               const u16* __restrict__ xg,
                                               u16* hbuf, int* flags,
                                               float* __restrict__ out) {
  __shared__ u16 Ws[64 * 1024];  // 128 KB
  const int bid = blockIdx.x;    // 0..63
  const int colbase = bid * 16;
  const int t = threadIdx.x;
  const int lane = t & 63, wv = t >> 6;

  // ---- stage W slice: Ws row r = hl*4+gate <- Whh row gate*1024 + colbase + hl
  {
    const int r = t >> 3;             // 0..63
    const int gate = r & 3, hl = r >> 2;
    const float* src = Whh + ((size_t)gate * 1024 + colbase + hl) * 1024;
    const int swz = r & 15;
#pragma unroll 4
    for (int j = 0; j < 16; ++j) {
      const int c = (t & 7) + j * 8;  // 16B chunk index, 0..127
      float4 w0 = *(const float4*)(src + c * 8);
      float4 w1 = *(const float4*)(src + c * 8 + 4);
      short8 v;
      v[0] = (short)f2bf(w0.x); v[1] = (short)f2bf(w0.y);
      v[2] = (short)f2bf(w0.z); v[3] = (short)f2bf(w0.w);
      v[4] = (short)f2bf(w1.x); v[5] = (short)f2bf(w1.y);
      v[6] = (short)f2bf(w1.z); v[7] = (short)f2bf(w1.w);
      *(short8*)(Ws + r * 1024 + ((c ^ swz) * 8)) = v;
    }
  }
  __syncthreads();

  const int n0 = lane & 15, kg = lane >> 4;
  const int nt = wv & 3;            // batch tile
  const int mp = wv >> 2;           // m-pair
  const int batch = nt * 16 + n0;
  const int hcA = colbase + mp * 8 + kg;   // hcol of tile A for this lane
  const int hcB = hcA + 4;                 // tile B
  const int mrowA = (2 * mp) * 16 + n0;    // Ws row base for A-frags
  const int mrowB = (2 * mp + 1) * 16 + n0;

  float cA = 0.f, cB = 0.f;
  const size_t xrow0 = (size_t)batch * NT;  // row index into xg rows

  // prefetch xg for step 0
  u16 xA[4], xB[4];
  {
    const u16* p = xg + xrow0 * NG;  // t = 0
#pragma unroll
    for (int g = 0; g < 4; ++g) { xA[g] = p[g * 1024 + hcA]; xB[g] = p[g * 1024 + hcB]; }
  }

  for (int s = 0; s < NT; ++s) {
    if (s) {
      if (wv == 0) {
        for (int it = 0; it < (1 << 18); ++it) {
          int f = __hip_atomic_load(&flags[lane], __ATOMIC_RELAXED, __HIP_MEMORY_SCOPE_AGENT);
#pragma unroll
          for (int o = 1; o < 64; o <<= 1) {
            int q = __shfl_xor(f, o, 64);
            f = f < q ? f : q;
          }
          if (f >= s) break;
          __builtin_amdgcn_s_sleep(1);
        }
        // acquire: one buffer_inv so plain loads below see fresh h
        (void)__hip_atomic_load(&flags[lane], __ATOMIC_ACQUIRE, __HIP_MEMORY_SCOPE_AGENT);
      }
      __syncthreads();
    }

    // ---- recurrent GEMM: A = Ws (LDS), B = h (global, natural layout)
    const u16* hr = hbuf + (size_t)(s & 1) * (NB * ND) + (size_t)batch * ND + kg * 8;
    f32x4 a0 = {0.f, 0.f, 0.f, 0.f}, a1 = {0.f, 0.f, 0.f, 0.f};
#pragma unroll 8
    for (int kk = 0; kk < 32; ++kk) {
      short8 bv = *(const short8*)(hr + kk * 32);
      const int ch = ((kg + kk * 4) ^ n0) * 8;
      short8 wA = *(const short8*)(Ws + mrowA * 1024 + ch);
      short8 wB = *(const short8*)(Ws + mrowB * 1024 + ch);
      a0 = __builtin_amdgcn_mfma_f32_16x16x32_bf16(wA, bv, a0, 0, 0, 0);
      a1 = __builtin_amdgcn_mfma_f32_16x16x32_bf16(wB, bv, a1, 0, 0, 0);
    }

    // ---- prefetch xg for step s+1 (issued after B-loads; consumed next step)
    u16 nA[4], nB[4];
    {
      const int sn = (s + 1 < NT) ? s + 1 : s;
      const u16* p = xg + (xrow0 + sn) * NG;
#pragma unroll
      for (int g = 0; g < 4; ++g) { nA[g] = p[g * 1024 + hcA]; nB[g] = p[g * 1024 + hcB]; }
    }

    // ---- elementwise LSTM cell (all 4 gates in-lane)
    float iA = sigmf(a0[0] + bf2f(xA[0]));
    float fA = sigmf(a0[1] + bf2f(xA[1]));
    float gA = tanhf2(a0[2] + bf2f(xA[2]));
    float oA = sigmf(a0[3] + bf2f(xA[3]));
    cA = fA * cA + iA * gA;
    float hA = oA * tanhf2(cA);

    float iB = sigmf(a1[0] + bf2f(xB[0]));
    float fB = sigmf(a1[1] + bf2f(xB[1]));
    float gB = tanhf2(a1[2] + bf2f(xB[2]));
    float oB = sigmf(a1[3] + bf2f(xB[3]));
    cB = fB * cB + iB * gB;
    float hB = oB * tanhf2(cB);

    // ---- pack 4 kg-lanes -> u64, store h_{s+1} via agent-scope atomics
    u16* hw = hbuf + (size_t)((s & 1) ^ 1) * (NB * ND);
    {
      u32 v = f2bf(hA);
      u32 ox = (u32)__shfl_xor((int)v, 16, 64);
      u32 pr = (kg & 1) ? ((ox & 0xffffu) | (v << 16)) : ((v & 0xffffu) | (ox << 16));
      u32 p2 = (u32)__shfl_xor((int)pr, 32, 64);
      u64 q = (kg & 2) ? (((u64)pr << 32) | p2) : ((u64)pr | ((u64)p2 << 32));
      if (kg == 0)
        __hip_atomic_store((u64*)(hw + (size_t)batch * ND + colbase + mp * 8), q,
                           __ATOMIC_RELAXED, __HIP_MEMORY_SCOPE_AGENT);
    }
    {
      u32 v = f2bf(hB);
      u32 ox = (u32)__shfl_xor((int)v, 16, 64);
      u32 pr = (kg & 1) ? ((ox & 0xffffu) | (v << 16)) : ((v & 0xffffu) | (ox << 16));
      u32 p2 = (u32)__shfl_xor((int)pr, 32, 64);
      u64 q = (kg & 2) ? (((u64)pr << 32) | p2) : ((u64)pr | ((u64)p2 << 32));
      if (kg == 0)
        __hip_atomic_store((u64*)(hw + (size_t)batch * ND + colbase + mp * 8 + 4), q,
                           __ATOMIC_RELAXED, __HIP_MEMORY_SCOPE_AGENT);
    }

    if (s == NT - 1) {
      out[(size_t)batch * ND + hcA] = hA;
      out[(size_t)batch * ND + hcB] = hB;
    }

    xA[0] = nA[0]; xA[1] = nA[1]; xA[2] = nA[2]; xA[3] = nA[3];
    xB[0] = nB[0]; xB[1] = nB[1]; xB[2] = nB[2]; xB[3] = nB[3];

    __syncthreads();  // all waves' h-stores drained (vmcnt 0) before flag
    if (t == 0)
      __hip_atomic_store(&flags[bid], s + 1, __ATOMIC_RELEASE, __HIP_MEMORY_SCOPE_AGENT);
  }
}

extern "C" void kernel_launch(void* const* d_in, const int* in_sizes, int n_in,
                              void* d_out, int out_size, void* d_ws, size_t ws_size,
                              hipStream_t stream) {
  const float* x = (const float*)d_in[0];
  const float* Wih = (const float*)d_in[1];
  const float* Whh = (const float*)d_in[2];
  const float* bih = (const float*)d_in[3];
  const float* bhh = (const float*)d_in[4];
  float* out = (float*)d_out;
  char* ws = (char*)d_ws;

  const size_t SZ_XB = (size_t)NB * NT * ND * 2;
  const size_t SZ_XG = (size_t)NB * NT * NG * 2;
  const size_t SZ_WB = (size_t)NG * ND * 2;
  const size_t SZ_BIAS = (size_t)NG * 4;
  const size_t SZ_H = (size_t)2 * NB * ND * 2;
  const size_t SZ_FLAGS = 1024;
  const size_t NEED = SZ_XB + SZ_XG + SZ_WB + SZ_BIAS + SZ_H + SZ_FLAGS;

  if (ws_size < NEED) {
    k_wsfail<<<256, 256, 0, stream>>>(out);
    return;
  }

  size_t off = 0;
  u16* xb = (u16*)(ws + off); off += SZ_XB;
  u16* xg = (u16*)(ws + off); off += SZ_XG;
  u16* wb = (u16*)(ws + off); off += SZ_WB;
  float* bias = (float*)(ws + off); off += SZ_BIAS;
  u16* hbuf = (u16*)(ws + off); off += SZ_H;
  int* flags = (int*)(ws + off); off += SZ_FLAGS;

  k_init<<<33, 256, 0, stream>>>((uint4*)hbuf, (uint4*)flags);
  k_convert<<<2048, 256, 0, stream>>>(x, Wih, bih, bhh, xb, wb, bias);
  k_gemm<<<8192, 256, 0, stream>>>(xb, wb, bias, xg);
  k_scan2<<<64, 512, 0, stream>>>(Whh, xg, hbuf, flags, out);
}